// Round 1
// baseline (1865.664 us; speedup 1.0000x reference)
//
#include <hip/hip_runtime.h>
#include <stdint.h>

#define T_DIM 512
#define B_DIM 512
#define I_DIM 128
#define H_DIM 128
#define G_DIM 384
#define STEPS 511   // reference scans t = 0..T-2

__device__ __forceinline__ unsigned bf16rne(float f) {
  unsigned u = __float_as_uint(f);
  return (u + 0x7fffu + ((u >> 16) & 1u)) >> 16;
}

// ---------------------------------------------------------------------------
// Kernel A: xp[row][g] = sum_k x[row][k] * W_ih[g][k] + b_ih[g]
// rows are chunk-local flat (t-t0)*512+b. Block = 192 threads, 32 rows,
// thread covers gates 2*tid, 2*tid+1. x tile staged in LDS (read-once from
// HBM); W_ih streamed from L2 (192 KB, hot).
// ---------------------------------------------------------------------------
__global__ __launch_bounds__(192) void k_xproj(
    const float* __restrict__ xch, const float* __restrict__ Wih,
    const float* __restrict__ bih, float* __restrict__ xp) {
  __shared__ float4 xt[32 * 32];  // [row][kc], kc = 4-float chunk of k
  const int tid = threadIdx.x;
  const int64_t row0 = (int64_t)blockIdx.x * 32;

  const float4* xsrc = (const float4*)(xch + row0 * I_DIM);
  for (int i = tid; i < 32 * 32; i += 192) xt[i] = xsrc[i];
  __syncthreads();

  const int g0 = 2 * tid, g1 = 2 * tid + 1;
  const float4* w0p = (const float4*)(Wih + (size_t)g0 * I_DIM);
  const float4* w1p = (const float4*)(Wih + (size_t)g1 * I_DIM);

  float acc0[32], acc1[32];
#pragma unroll
  for (int r = 0; r < 32; ++r) { acc0[r] = 0.f; acc1[r] = 0.f; }

  for (int kc = 0; kc < 32; ++kc) {
    const float4 w0 = w0p[kc];
    const float4 w1 = w1p[kc];
#pragma unroll
    for (int r = 0; r < 32; ++r) {
      const float4 xv = xt[r * 32 + kc];  // broadcast read (same addr/wave)
      acc0[r] = fmaf(xv.x, w0.x, acc0[r]);
      acc0[r] = fmaf(xv.y, w0.y, acc0[r]);
      acc0[r] = fmaf(xv.z, w0.z, acc0[r]);
      acc0[r] = fmaf(xv.w, w0.w, acc0[r]);
      acc1[r] = fmaf(xv.x, w1.x, acc1[r]);
      acc1[r] = fmaf(xv.y, w1.y, acc1[r]);
      acc1[r] = fmaf(xv.z, w1.z, acc1[r]);
      acc1[r] = fmaf(xv.w, w1.w, acc1[r]);
    }
  }

  const float b0 = bih[g0], b1 = bih[g1];
#pragma unroll 4
  for (int r = 0; r < 32; ++r) {
    float2 o;
    o.x = acc0[r] + b0;
    o.y = acc1[r] + b1;
    *(float2*)(xp + (size_t)(row0 + r) * G_DIM + g0) = o;  // coalesced
  }
}

// ---------------------------------------------------------------------------
// Kernel B: the sequential recurrence. 256 blocks x 2 batch rows, 768 threads.
// Thread = (gate g in [0,384), k-half in {0,1}). W_hh staged in LDS as bf16
// pairs with XOR swizzle (2-way bank aliasing = free). h kept fp32 in LDS.
// 3 barriers/step. NLL accumulated per block across chunk launches into
// nll_part[block] (single writer per slot -> deterministic).
// ---------------------------------------------------------------------------
__global__ __launch_bounds__(768) void k_rec(
    const float* __restrict__ xp, const float* __restrict__ gt,
    const float* __restrict__ Whh, const float* __restrict__ bhh,
    const float* __restrict__ Wdec, const float* __restrict__ bdec,
    float* __restrict__ ws_h, float* __restrict__ nll_part,
    int t0, int t1, int first) {
  __shared__ uint2 wl[G_DIM][32];                 // 96 KB bf16 W_hh, swizzled
  __shared__ __align__(16) float h_lds[2][H_DIM];
  __shared__ float r_lds[2][H_DIM];
  __shared__ float z_lds[2][H_DIM];
  __shared__ float p_lds[2][H_DIM];
  __shared__ float pp[2][G_DIM];                  // k-split partials

  const int tid = threadIdx.x;
  const int half = (tid >= G_DIM) ? 1 : 0;
  const int g = half ? tid - G_DIM : tid;
  const int row0 = blockIdx.x * 2;

  if (!half) {
    const float4* wr = (const float4*)(Whh + (size_t)g * H_DIM);
    for (int kc = 0; kc < 32; ++kc) {
      const float4 w = wr[kc];
      uint2 pk;
      pk.x = bf16rne(w.x) | (bf16rne(w.y) << 16);
      pk.y = bf16rne(w.z) | (bf16rne(w.w) << 16);
      wl[g][kc ^ (g & 31)] = pk;
    }
    if (tid < H_DIM) {
      h_lds[0][tid] = first ? 0.f : ws_h[(size_t)row0 * H_DIM + tid];
      h_lds[1][tid] = first ? 0.f : ws_h[(size_t)(row0 + 1) * H_DIM + tid];
    }
  }
  const float bh = bhh[g];
  float wdj = 0.f;
  if (tid >= 256 && tid < 384) wdj = Wdec[tid - 256];
  const float bd0 = bdec[0];
  __syncthreads();

  float nll_acc = 0.f;

  for (int s = t0; s < t1; ++s) {
    const int lt = s - t0;
    float xp0 = 0.f, xp1 = 0.f;
    if (!half) {  // issue global loads early; hidden under hp loop
      const float* xpr = xp + ((size_t)lt * B_DIM + row0) * G_DIM;
      xp0 = xpr[g];
      xp1 = xpr[G_DIM + g];
    }

    float hp0 = half ? 0.f : bh;
    float hp1 = half ? 0.f : bh;
    const int kbase = half ? 16 : 0;
#pragma unroll 8
    for (int kk = 0; kk < 16; ++kk) {
      const int kc = kbase + kk;
      const uint2 wv = wl[g][kc ^ (g & 31)];
      const float4 ha = *(const float4*)&h_lds[0][kc * 4];  // broadcast
      const float4 hb = *(const float4*)&h_lds[1][kc * 4];  // broadcast
      const float w0 = __uint_as_float(wv.x << 16);
      const float w1 = __uint_as_float(wv.x & 0xffff0000u);
      const float w2 = __uint_as_float(wv.y << 16);
      const float w3 = __uint_as_float(wv.y & 0xffff0000u);
      hp0 = fmaf(ha.x, w0, hp0); hp0 = fmaf(ha.y, w1, hp0);
      hp0 = fmaf(ha.z, w2, hp0); hp0 = fmaf(ha.w, w3, hp0);
      hp1 = fmaf(hb.x, w0, hp1); hp1 = fmaf(hb.y, w1, hp1);
      hp1 = fmaf(hb.z, w2, hp1); hp1 = fmaf(hb.w, w3, hp1);
    }
    if (half) { pp[0][g] = hp0; pp[1][g] = hp1; }
    __syncthreads();  // barrier 1: partials ready; all h_lds reads done

    if (!half) {
      hp0 += pp[0][g];
      hp1 += pp[1][g];
      if (tid < 128) {
        r_lds[0][tid] = 1.f / (1.f + expf(-(xp0 + hp0)));
        r_lds[1][tid] = 1.f / (1.f + expf(-(xp1 + hp1)));
      } else if (tid < 256) {
        const int j = tid - 128;
        z_lds[0][j] = 1.f / (1.f + expf(-(xp0 + hp0)));
        z_lds[1][j] = 1.f / (1.f + expf(-(xp1 + hp1)));
      }
    }
    __syncthreads();  // barrier 2: r,z ready

    if (!half && tid >= 256) {
      const int j = tid - 256;
      const float n0 = tanhf(xp0 + r_lds[0][j] * hp0);
      const float n1 = tanhf(xp1 + r_lds[1][j] * hp1);
      const float z0 = z_lds[0][j], z1 = z_lds[1][j];
      const float h0 = h_lds[0][j], h1 = h_lds[1][j];
      const float hn0 = (1.f - z0) * n0 + z0 * h0;
      const float hn1 = (1.f - z1) * n1 + z1 * h1;
      h_lds[0][j] = hn0;
      h_lds[1][j] = hn1;
      p_lds[0][j] = hn0 * wdj;
      p_lds[1][j] = hn1 * wdj;
    }
    __syncthreads();  // barrier 3: h_new + decode partials ready

    if (tid < 128) {  // waves 0,1: decode + NLL for rows 0,1
      const int r = tid >> 6, l = tid & 63;
      float v = p_lds[r][l] + p_lds[r][l + 64];
      for (int off = 32; off; off >>= 1) v += __shfl_down(v, off);
      if (l == 0) {
        const float C = 1.f / (1.f + expf(-(v + bd0)));
        const float gtv = gt[(size_t)(s + 1) * B_DIM + row0 + r];
        nll_acc -= gtv * logf(C + 1e-4f) + (1.f - gtv) * logf(1.f - C + 1e-4f);
      }
    }
  }

  // persist h for next chunk launch
  if (!half && tid >= 256) {
    const int j = tid - 256;
    ws_h[(size_t)row0 * H_DIM + j] = h_lds[0][j];
    ws_h[(size_t)(row0 + 1) * H_DIM + j] = h_lds[1][j];
  }
  // combine the two per-row NLL accumulators (tid 0 and tid 64)
  if (tid == 0) pp[0][0] = nll_acc;
  if (tid == 64) pp[0][1] = nll_acc;
  __syncthreads();
  if (tid == 0) {
    const float s2 = pp[0][0] + pp[0][1];
    nll_part[blockIdx.x] = first ? s2 : (nll_part[blockIdx.x] + s2);
  }
}

// ---------------------------------------------------------------------------
// Finalize: sum 256 per-block partials, divide by gt.size = T*B.
// ---------------------------------------------------------------------------
__global__ __launch_bounds__(256) void k_fin(const float* __restrict__ nll_part,
                                             float* __restrict__ out) {
  __shared__ float red[4];
  const int tid = threadIdx.x;
  float v = nll_part[tid];
  for (int off = 32; off; off >>= 1) v += __shfl_down(v, off);
  if ((tid & 63) == 0) red[tid >> 6] = v;
  __syncthreads();
  if (tid == 0)
    out[0] = (red[0] + red[1] + red[2] + red[3]) * (1.f / (512.f * 512.f));
}

// ---------------------------------------------------------------------------
extern "C" void kernel_launch(void* const* d_in, const int* in_sizes, int n_in,
                              void* d_out, int out_size, void* d_ws,
                              size_t ws_size, hipStream_t stream) {
  const float* x    = (const float*)d_in[0];
  const float* gt   = (const float*)d_in[1];
  const float* Wih  = (const float*)d_in[2];
  const float* Whh  = (const float*)d_in[3];
  const float* bih  = (const float*)d_in[4];
  const float* bhh  = (const float*)d_in[5];
  const float* Wdec = (const float*)d_in[6];
  const float* bdec = (const float*)d_in[7];

  // ws layout: [0,1KB) nll_part[256]; [4KB, 4KB+256KB) h state; then xp chunk
  float* nll_part = (float*)d_ws;
  float* ws_h = (float*)((char*)d_ws + 4096);
  const size_t xp_off = 4096 + (size_t)B_DIM * H_DIM * 4;  // 266240
  float* xp = (float*)((char*)d_ws + xp_off);

  const size_t chunk_bytes = (size_t)B_DIM * G_DIM * 4;  // per timestep
  size_t avail = ws_size > xp_off ? ws_size - xp_off : 0;
  int Tc = (int)(avail / chunk_bytes);
  if (Tc > 64) Tc = 64;        // keep xp chunk (<=50 MB) L3-resident
  if (Tc < 1) Tc = 1;

  for (int t0 = 0; t0 < STEPS; t0 += Tc) {
    int t1 = t0 + Tc;
    if (t1 > STEPS) t1 = STEPS;
    const int nt = t1 - t0;
    k_xproj<<<dim3(nt * 16), dim3(192), 0, stream>>>(
        x + (size_t)t0 * B_DIM * I_DIM, Wih, bih, xp);
    k_rec<<<dim3(256), dim3(768), 0, stream>>>(
        xp, gt, Whh, bhh, Wdec, bdec, ws_h, nll_part, t0, t1, t0 == 0 ? 1 : 0);
  }
  k_fin<<<dim3(1), dim3(256), 0, stream>>>(nll_part, (float*)d_out);
}

// Round 2
// 1177.320 us; speedup vs baseline: 1.5847x; 1.5847x over previous
//
#include <hip/hip_runtime.h>
#include <stdint.h>

#define T_DIM 512
#define B_DIM 512
#define I_DIM 128
#define H_DIM 128
#define G_DIM 384
#define STEPS 511   // reference scans t = 0..T-2

// ---------------------------------------------------------------------------
// Kernel A: xp[row][g] = sum_k x[row][k] * W_ih[g][k] + b_ih[g]
// (unchanged from round 1 — ~62 TF fp32; MFMA conversion is a later round)
// ---------------------------------------------------------------------------
__global__ __launch_bounds__(192) void k_xproj(
    const float* __restrict__ xch, const float* __restrict__ Wih,
    const float* __restrict__ bih, float* __restrict__ xp) {
  __shared__ float4 xt[32 * 32];  // [row][kc], kc = 4-float chunk of k
  const int tid = threadIdx.x;
  const int64_t row0 = (int64_t)blockIdx.x * 32;

  const float4* xsrc = (const float4*)(xch + row0 * I_DIM);
  for (int i = tid; i < 32 * 32; i += 192) xt[i] = xsrc[i];
  __syncthreads();

  const int g0 = 2 * tid, g1 = 2 * tid + 1;
  const float4* w0p = (const float4*)(Wih + (size_t)g0 * I_DIM);
  const float4* w1p = (const float4*)(Wih + (size_t)g1 * I_DIM);

  float acc0[32], acc1[32];
#pragma unroll
  for (int r = 0; r < 32; ++r) { acc0[r] = 0.f; acc1[r] = 0.f; }

  for (int kc = 0; kc < 32; ++kc) {
    const float4 w0 = w0p[kc];
    const float4 w1 = w1p[kc];
#pragma unroll
    for (int r = 0; r < 32; ++r) {
      const float4 xv = xt[r * 32 + kc];  // broadcast read (same addr/wave)
      acc0[r] = fmaf(xv.x, w0.x, acc0[r]);
      acc0[r] = fmaf(xv.y, w0.y, acc0[r]);
      acc0[r] = fmaf(xv.z, w0.z, acc0[r]);
      acc0[r] = fmaf(xv.w, w0.w, acc0[r]);
      acc1[r] = fmaf(xv.x, w1.x, acc1[r]);
      acc1[r] = fmaf(xv.y, w1.y, acc1[r]);
      acc1[r] = fmaf(xv.z, w1.z, acc1[r]);
      acc1[r] = fmaf(xv.w, w1.w, acc1[r]);
    }
  }

  const float b0 = bih[g0], b1 = bih[g1];
#pragma unroll 4
  for (int r = 0; r < 32; ++r) {
    float2 o;
    o.x = acc0[r] + b0;
    o.y = acc1[r] + b1;
    *(float2*)(xp + (size_t)(row0 + r) * G_DIM + g0) = o;  // coalesced
  }
}

// ---------------------------------------------------------------------------
// Kernel B: sequential GRU recurrence. 256 blocks x 2 batch rows, 768 threads
// (12 waves). Thread = (gidx in [0,192), split in [0,4)): owns gates
// {2*gidx, 2*gidx+1} and K-slice [32*split, 32*split+32). W_hh held in
// REGISTERS as fp32 (64 VGPR, loaded once). Per step:
//   phase A: 128 FMAs from 16 broadcast b128 h-reads; write float2 partials
//            (conflict-free layout pp[row][split][g]); stage xp row to LDS.
//   barrier 1
//   phase B: 256 threads combine partials, gate nonlinearities, h update,
//            decode partial p = h_new * W_dec[j].
//   barrier 2
// Decode reduce + NLL for step s-1 runs at the TOP of step s (overlapped
// with FMA issue on waves 0-1). 2 barriers/step.
// ---------------------------------------------------------------------------
__global__ __launch_bounds__(768, 3) void k_rec(
    const float* __restrict__ xp, const float* __restrict__ gt,
    const float* __restrict__ Whh, const float* __restrict__ bhh,
    const float* __restrict__ Wdec, const float* __restrict__ bdec,
    float* __restrict__ ws_h, float* __restrict__ nll_part,
    int t0, int t1, int first) {
  __shared__ float pp[2][4][G_DIM];               // [row][split][gate] partials
  __shared__ float xl[2][G_DIM];                  // staged xp for this step
  __shared__ __align__(16) float h_lds[2][H_DIM];
  __shared__ float p_lds[2][H_DIM];               // decode partials
  __shared__ float red_s[2];

  const int tid = threadIdx.x;
  const int gidx = tid % 192;
  const int split = tid / 192;          // wave-uniform (192 = 3 waves)
  const int g0 = gidx * 2;
  const int row0 = blockIdx.x * 2;

  // xp staging map: one value per thread
  const int srow = (tid >= G_DIM) ? 1 : 0;
  const int sg = srow ? tid - G_DIM : tid;

  // ---- one-time: W_hh slice into registers (fp32) ----
  float4 w0[8], w1[8];
  {
    const float4* wp0 = (const float4*)(Whh + (size_t)g0 * H_DIM + split * 32);
    const float4* wp1 = (const float4*)(Whh + (size_t)(g0 + 1) * H_DIM + split * 32);
#pragma unroll
    for (int c = 0; c < 8; ++c) { w0[c] = wp0[c]; w1[c] = wp1[c]; }
  }
  const float bh0 = (split == 0) ? bhh[g0] : 0.f;
  const float bh1 = (split == 0) ? bhh[g0 + 1] : 0.f;

  // phase-B identity (valid for tid < 256)
  const int prow = (tid >> 7) & 1;
  const int pj = tid & 127;
  const float wdj = (tid < 256) ? Wdec[pj] : 0.f;
  const float bd0 = bdec[0];

  if (tid < 256) {
    h_lds[prow][pj] = first ? 0.f : ws_h[(size_t)(row0 + prow) * H_DIM + pj];
  }
  __syncthreads();

  float nll0 = 0.f;  // accumulated by lanes tid==0 (row0) and tid==64 (row1)

  const float4* h4a = (const float4*)h_lds[0];
  const float4* h4b = (const float4*)h_lds[1];
  const int kb = split * 8;

  for (int s = t0; s < t1; ++s) {
    const int lt = s - t0;
    // issue this step's xp load early; consumed only at the xl write below
    const float xg = xp[((size_t)lt * B_DIM + row0 + srow) * G_DIM + sg];

    // decode + NLL for the PREVIOUS step (p_lds stable until next barrier 1)
    if (s > t0 && tid < 128) {
      const int r = tid >> 6, l = tid & 63;
      float v = p_lds[r][l] + p_lds[r][l + 64];
#pragma unroll
      for (int off = 32; off; off >>= 1) v += __shfl_down(v, off);
      if (l == 0) {
        const float C = 1.f / (1.f + __expf(-(v + bd0)));
        const float gtv = gt[(size_t)s * B_DIM + row0 + r];
        nll0 -= gtv * __logf(C + 1e-4f) +
                (1.f - gtv) * __logf(1.f - C + 1e-4f);
      }
    }

    // ---- phase A: K-sliced gemv from registers ----
    float a00 = bh0, a01 = bh0;  // gate g0, rows 0/1
    float a10 = bh1, a11 = bh1;  // gate g0+1, rows 0/1
#pragma unroll
    for (int c = 0; c < 8; ++c) {
      const float4 ha = h4a[kb + c];  // broadcast (wave-uniform addr)
      const float4 hb = h4b[kb + c];
      a00 = fmaf(ha.x, w0[c].x, a00); a00 = fmaf(ha.y, w0[c].y, a00);
      a00 = fmaf(ha.z, w0[c].z, a00); a00 = fmaf(ha.w, w0[c].w, a00);
      a01 = fmaf(hb.x, w0[c].x, a01); a01 = fmaf(hb.y, w0[c].y, a01);
      a01 = fmaf(hb.z, w0[c].z, a01); a01 = fmaf(hb.w, w0[c].w, a01);
      a10 = fmaf(ha.x, w1[c].x, a10); a10 = fmaf(ha.y, w1[c].y, a10);
      a10 = fmaf(ha.z, w1[c].z, a10); a10 = fmaf(ha.w, w1[c].w, a10);
      a11 = fmaf(hb.x, w1[c].x, a11); a11 = fmaf(hb.y, w1[c].y, a11);
      a11 = fmaf(hb.z, w1[c].z, a11); a11 = fmaf(hb.w, w1[c].w, a11);
    }
    // conflict-free partial writes (lane stride 8B = 2-way = free)
    *(float2*)&pp[0][split][g0] = make_float2(a00, a10);
    *(float2*)&pp[1][split][g0] = make_float2(a01, a11);
    xl[srow][sg] = xg;
    __syncthreads();  // barrier 1: partials + xl ready

    // ---- phase B: gate math on 256 threads (one per row,j) ----
    if (tid < 256) {
      const float rp = pp[prow][0][pj] + pp[prow][1][pj] +
                       pp[prow][2][pj] + pp[prow][3][pj] + xl[prow][pj];
      const float zp = pp[prow][0][128 + pj] + pp[prow][1][128 + pj] +
                       pp[prow][2][128 + pj] + pp[prow][3][128 + pj] +
                       xl[prow][128 + pj];
      const float hn = pp[prow][0][256 + pj] + pp[prow][1][256 + pj] +
                       pp[prow][2][256 + pj] + pp[prow][3][256 + pj];
      const float xn = xl[prow][256 + pj];
      const float r_ = 1.f / (1.f + __expf(-rp));
      const float z_ = 1.f / (1.f + __expf(-zp));
      const float e2 = __expf(2.f * (xn + r_ * hn));
      const float n_ = 1.f - 2.f / (e2 + 1.f);
      const float hold = h_lds[prow][pj];
      const float hnew = (1.f - z_) * n_ + z_ * hold;
      h_lds[prow][pj] = hnew;
      p_lds[prow][pj] = hnew * wdj;
    }
    __syncthreads();  // barrier 2: h_new + decode partials ready
  }

  // trailing decode for s = t1-1
  if (tid < 128) {
    const int r = tid >> 6, l = tid & 63;
    float v = p_lds[r][l] + p_lds[r][l + 64];
#pragma unroll
    for (int off = 32; off; off >>= 1) v += __shfl_down(v, off);
    if (l == 0) {
      const float C = 1.f / (1.f + __expf(-(v + bd0)));
      const float gtv = gt[(size_t)t1 * B_DIM + row0 + r];
      nll0 -= gtv * __logf(C + 1e-4f) +
              (1.f - gtv) * __logf(1.f - C + 1e-4f);
    }
  }

  // persist h for next chunk launch
  if (tid < 256) {
    ws_h[(size_t)(row0 + prow) * H_DIM + pj] = h_lds[prow][pj];
  }

  // combine the two per-row NLL accumulators
  if (tid == 0) red_s[0] = nll0;
  if (tid == 64) red_s[1] = nll0;
  __syncthreads();
  if (tid == 0) {
    const float s2 = red_s[0] + red_s[1];
    nll_part[blockIdx.x] = first ? s2 : (nll_part[blockIdx.x] + s2);
  }
}

// ---------------------------------------------------------------------------
// Finalize: sum 256 per-block partials, divide by gt.size = T*B.
// ---------------------------------------------------------------------------
__global__ __launch_bounds__(256) void k_fin(const float* __restrict__ nll_part,
                                             float* __restrict__ out) {
  __shared__ float red[4];
  const int tid = threadIdx.x;
  float v = nll_part[tid];
  for (int off = 32; off; off >>= 1) v += __shfl_down(v, off);
  if ((tid & 63) == 0) red[tid >> 6] = v;
  __syncthreads();
  if (tid == 0)
    out[0] = (red[0] + red[1] + red[2] + red[3]) * (1.f / (512.f * 512.f));
}

// ---------------------------------------------------------------------------
extern "C" void kernel_launch(void* const* d_in, const int* in_sizes, int n_in,
                              void* d_out, int out_size, void* d_ws,
                              size_t ws_size, hipStream_t stream) {
  const float* x    = (const float*)d_in[0];
  const float* gt   = (const float*)d_in[1];
  const float* Wih  = (const float*)d_in[2];
  const float* Whh  = (const float*)d_in[3];
  const float* bih  = (const float*)d_in[4];
  const float* bhh  = (const float*)d_in[5];
  const float* Wdec = (const float*)d_in[6];
  const float* bdec = (const float*)d_in[7];

  // ws layout: [0,1KB) nll_part[256]; [4KB, 4KB+256KB) h state; then xp chunk
  float* nll_part = (float*)d_ws;
  float* ws_h = (float*)((char*)d_ws + 4096);
  const size_t xp_off = 4096 + (size_t)B_DIM * H_DIM * 4;  // 266240
  float* xp = (float*)((char*)d_ws + xp_off);

  const size_t chunk_bytes = (size_t)B_DIM * G_DIM * 4;  // per timestep
  size_t avail = ws_size > xp_off ? ws_size - xp_off : 0;
  int Tc = (int)(avail / chunk_bytes);
  if (Tc > 64) Tc = 64;        // keep xp chunk (<=50 MB) L3-resident
  if (Tc < 1) Tc = 1;

  for (int t0 = 0; t0 < STEPS; t0 += Tc) {
    int t1 = t0 + Tc;
    if (t1 > STEPS) t1 = STEPS;
    const int nt = t1 - t0;
    k_xproj<<<dim3(nt * 16), dim3(192), 0, stream>>>(
        x + (size_t)t0 * B_DIM * I_DIM, Wih, bih, xp);
    k_rec<<<dim3(256), dim3(768), 0, stream>>>(
        xp, gt, Whh, bhh, Wdec, bdec, ws_h, nll_part, t0, t1, t0 == 0 ? 1 : 0);
  }
  k_fin<<<dim3(1), dim3(256), 0, stream>>>(nll_part, (float*)d_out);
}

// Round 3
// 915.325 us; speedup vs baseline: 2.0383x; 1.2862x over previous
//
#include <hip/hip_runtime.h>
#include <stdint.h>

#define B_DIM 512
#define I_DIM 128
#define H_DIM 128
#define G_DIM 384
#define STEPS 511   // reference scans t = 0..T-2

typedef __attribute__((ext_vector_type(8))) short bf16x8;
typedef __attribute__((ext_vector_type(4))) float f32x4;
typedef _Float16 half2_t __attribute__((ext_vector_type(2)));

__device__ __forceinline__ unsigned bf16rne(float f) {
  unsigned u = __float_as_uint(f);
  return (u + 0x7fffu + ((u >> 16) & 1u)) >> 16;
}
__device__ __forceinline__ short bf16s(float f) { return (short)bf16rne(f); }

__device__ __forceinline__ float fdot2(half2_t a, half2_t b, float c) {
#if __has_builtin(__builtin_amdgcn_fdot2)
  return __builtin_amdgcn_fdot2(a, b, c, false);
#else
  return fmaf((float)a.x, (float)b.x, fmaf((float)a.y, (float)b.y, c));
#endif
}

// ---------------------------------------------------------------------------
// Kernel A (MFMA): xp[row][g] = x[row][:] . Wih[g][:] + bih[g]
// Tile: 128 rows x 64 gate-cols, K=128 full. 256 threads = 4 waves,
// wave = (mh = w&1, nh = w>>1): 4 M-frags x 2 N-frags, 4 K-steps.
// A (x fp32 -> bf16) staged in LDS with XOR swizzle byte^=((row&7)<<4),
// applied on BOTH write and read. B frags (Wih) register-resident.
// ---------------------------------------------------------------------------
__global__ __launch_bounds__(256) void k_xproj(
    const float* __restrict__ xch, const float* __restrict__ Wih,
    const float* __restrict__ bih, float* __restrict__ xp) {
  __shared__ __align__(16) char As[128 * 128 * 2];  // 32 KB bf16 A tile
  const int tid = threadIdx.x;
  const int lane = tid & 63;
  const int wave = tid >> 6;
  const int mh = wave & 1, nh = wave >> 1;
  const int l15 = lane & 15, l4 = lane >> 4;

  // ---- stage A tile: global fp32 (coalesced float4) -> bf16 LDS ----
  const float4* xs = (const float4*)(xch + (size_t)blockIdx.x * 128 * I_DIM);
#pragma unroll
  for (int q = 0; q < 16; ++q) {
    const int fi = tid + 256 * q;           // float4 index in 128x128 tile
    const int row = fi >> 5, kq = fi & 31;  // kq: which 4-float chunk
    const float4 v = xs[fi];
    uint2 p;
    p.x = bf16rne(v.x) | (bf16rne(v.y) << 16);
    p.y = bf16rne(v.z) | (bf16rne(v.w) << 16);
    *(uint2*)(As + (row << 8) + (((kq << 3)) ^ ((row & 7) << 4))) = p;
  }

  // ---- B fragments from global (loop-invariant, registers) ----
  bf16x8 bf[2][4];
  float bv[2];
#pragma unroll
  for (int nf = 0; nf < 2; ++nf) {
    const int col = blockIdx.y * 64 + nh * 32 + nf * 16 + l15;
    bv[nf] = bih[col];
#pragma unroll
    for (int ks = 0; ks < 4; ++ks) {
      const float* wr = Wih + (size_t)col * I_DIM + ks * 32 + l4 * 8;
      const float4 wa = *(const float4*)wr;
      const float4 wb = *(const float4*)(wr + 4);
      bf16x8 b;
      b[0] = bf16s(wa.x); b[1] = bf16s(wa.y); b[2] = bf16s(wa.z); b[3] = bf16s(wa.w);
      b[4] = bf16s(wb.x); b[5] = bf16s(wb.y); b[6] = bf16s(wb.z); b[7] = bf16s(wb.w);
      bf[nf][ks] = b;
    }
  }
  __syncthreads();

  // ---- MFMA main: 4 ksteps x (4 A-reads + 8 MFMA) ----
  f32x4 acc[4][2];
#pragma unroll
  for (int m = 0; m < 4; ++m)
#pragma unroll
    for (int nf = 0; nf < 2; ++nf) acc[m][nf] = (f32x4){0.f, 0.f, 0.f, 0.f};

#pragma unroll
  for (int ks = 0; ks < 4; ++ks) {
#pragma unroll
    for (int m = 0; m < 4; ++m) {
      const int arow = mh * 64 + m * 16 + l15;
      const int kbyte = ks * 64 + l4 * 16;
      const bf16x8 a =
          *(const bf16x8*)(As + (arow << 8) + (kbyte ^ ((arow & 7) << 4)));
      acc[m][0] = __builtin_amdgcn_mfma_f32_16x16x32_bf16(a, bf[0][ks], acc[m][0], 0, 0, 0);
      acc[m][1] = __builtin_amdgcn_mfma_f32_16x16x32_bf16(a, bf[1][ks], acc[m][1], 0, 0, 0);
    }
  }

  // ---- epilogue: D[row=(l>>4)*4+r][col=l&15] ----
#pragma unroll
  for (int m = 0; m < 4; ++m) {
    const size_t row0 = (size_t)blockIdx.x * 128 + mh * 64 + m * 16 + l4 * 4;
#pragma unroll
    for (int nf = 0; nf < 2; ++nf) {
      const int col = blockIdx.y * 64 + nh * 32 + nf * 16 + l15;
#pragma unroll
      for (int r = 0; r < 4; ++r)
        xp[(row0 + r) * G_DIM + col] = acc[m][nf][r] + bv[nf];
    }
  }
}

// ---------------------------------------------------------------------------
// Kernel B: GRU recurrence. 512 blocks x 1 batch row, 512 threads (8 waves),
// 2 blocks/CU. Thread = (j = tid&127, split = tid>>7). Weights f16-packed in
// registers (48 half2), h f16-packed in LDS (broadcast b128 reads), dot2 FMA.
// 2 barriers/step; decode of step s-1 overlapped at top of step s.
// ---------------------------------------------------------------------------
__global__ __launch_bounds__(512, 4) void k_rec(
    const float* __restrict__ xp, const float* __restrict__ gt,
    const float* __restrict__ Whh, const float* __restrict__ bhh,
    const float* __restrict__ Wdec, const float* __restrict__ bdec,
    float* __restrict__ ws_h, float* __restrict__ nll_part,
    int t0, int t1, int first) {
  __shared__ float pp[4][3][H_DIM];               // [split][r,z,hn][j]
  __shared__ float xl[G_DIM];
  __shared__ float h_lds[H_DIM];
  __shared__ __align__(16) half2_t h2v[H_DIM / 2];
  __shared__ float p_lds[H_DIM];

  const int tid = threadIdx.x;
  const int j = tid & 127;
  const int split = tid >> 7;   // wave-uniform (2 waves per split)
  const int row = blockIdx.x;

  // ---- one-time: W_hh slice -> f16 packed registers ----
  half2_t wg[3][16];
#pragma unroll
  for (int g3 = 0; g3 < 3; ++g3) {
    const float4* wp =
        (const float4*)(Whh + ((size_t)(g3 * 128 + j)) * H_DIM + split * 32);
#pragma unroll
    for (int q = 0; q < 8; ++q) {
      const float4 w = wp[q];
      half2_t a, b;
      a.x = (_Float16)w.x; a.y = (_Float16)w.y;
      b.x = (_Float16)w.z; b.y = (_Float16)w.w;
      wg[g3][2 * q] = a;
      wg[g3][2 * q + 1] = b;
    }
  }
  const float bhr = bhh[j], bhz = bhh[128 + j], bhn = bhh[256 + j];
  const float wdj = Wdec[j];
  const float bd0 = bdec[0];

  // ---- init h ----
  if (tid < 128) {
    const float hv = first ? 0.f : ws_h[(size_t)row * H_DIM + j];
    h_lds[j] = hv;
    const float hb = __shfl_xor(hv, 1);
    if (!(j & 1)) {
      half2_t hp; hp.x = (_Float16)hv; hp.y = (_Float16)hb;
      h2v[j >> 1] = hp;
    }
  }
  __syncthreads();

  float nll0 = 0.f;
  float g_cur = 0.f;
  float xg = (tid < G_DIM)
                 ? xp[((size_t)0 * B_DIM + row) * G_DIM + tid]
                 : 0.f;  // prefetch step t0

  const float4* hv4 = (const float4*)h2v;

  for (int s = t0; s < t1; ++s) {
    // prefetch next step's xp value and gt
    float xg_next = 0.f;
    if (s + 1 < t1 && tid < G_DIM)
      xg_next = xp[((size_t)(s + 1 - t0) * B_DIM + row) * G_DIM + tid];
    float g_next = (tid < 64) ? gt[(size_t)(s + 1) * B_DIM + row] : 0.f;

    // decode + NLL for step s-1 (p_lds stable until barrier 1)
    if (s > t0 && tid < 64) {
      float v = p_lds[tid] + p_lds[tid + 64];
#pragma unroll
      for (int off = 32; off; off >>= 1) v += __shfl_down(v, off);
      if (tid == 0) {
        const float C = 1.f / (1.f + __expf(-(v + bd0)));
        nll0 -= g_cur * __logf(C + 1e-4f) +
                (1.f - g_cur) * __logf(1.f - C + 1e-4f);
      }
    }

    // ---- phase A: dot2 gemv from registers, h broadcast from LDS ----
    float aR = 0.f, aZ = 0.f, aHN = 0.f;
#pragma unroll
    for (int c4 = 0; c4 < 4; ++c4) {
      const float4 hq = hv4[split * 4 + c4];  // wave-uniform -> broadcast
      const half2_t h0 = __builtin_bit_cast(half2_t, hq.x);
      const half2_t h1 = __builtin_bit_cast(half2_t, hq.y);
      const half2_t h2 = __builtin_bit_cast(half2_t, hq.z);
      const half2_t h3 = __builtin_bit_cast(half2_t, hq.w);
      aR = fdot2(h0, wg[0][c4 * 4 + 0], aR);
      aZ = fdot2(h0, wg[1][c4 * 4 + 0], aZ);
      aHN = fdot2(h0, wg[2][c4 * 4 + 0], aHN);
      aR = fdot2(h1, wg[0][c4 * 4 + 1], aR);
      aZ = fdot2(h1, wg[1][c4 * 4 + 1], aZ);
      aHN = fdot2(h1, wg[2][c4 * 4 + 1], aHN);
      aR = fdot2(h2, wg[0][c4 * 4 + 2], aR);
      aZ = fdot2(h2, wg[1][c4 * 4 + 2], aZ);
      aHN = fdot2(h2, wg[2][c4 * 4 + 2], aHN);
      aR = fdot2(h3, wg[0][c4 * 4 + 3], aR);
      aZ = fdot2(h3, wg[1][c4 * 4 + 3], aZ);
      aHN = fdot2(h3, wg[2][c4 * 4 + 3], aHN);
    }
    pp[split][0][j] = aR;
    pp[split][1][j] = aZ;
    pp[split][2][j] = aHN;
    if (tid < G_DIM) xl[tid] = xg;
    __syncthreads();  // barrier 1: partials + xl ready; h2v reads done

    // ---- phase B: gate math on 128 threads ----
    if (tid < 128) {
      const float rp = pp[0][0][j] + pp[1][0][j] + pp[2][0][j] + pp[3][0][j] +
                       xl[j] + bhr;
      const float zp = pp[0][1][j] + pp[1][1][j] + pp[2][1][j] + pp[3][1][j] +
                       xl[128 + j] + bhz;
      const float hn = pp[0][2][j] + pp[1][2][j] + pp[2][2][j] + pp[3][2][j] +
                       bhn;
      const float xn = xl[256 + j];
      const float r_ = 1.f / (1.f + __expf(-rp));
      const float z_ = 1.f / (1.f + __expf(-zp));
      const float e2 = __expf(2.f * (xn + r_ * hn));
      const float n_ = 1.f - 2.f / (e2 + 1.f);
      const float hold = h_lds[j];
      const float hnew = (1.f - z_) * n_ + z_ * hold;
      h_lds[j] = hnew;
      p_lds[j] = hnew * wdj;
      const float hb = __shfl_xor(hnew, 1);
      if (!(j & 1)) {
        half2_t hp; hp.x = (_Float16)hnew; hp.y = (_Float16)hb;
        h2v[j >> 1] = hp;
      }
    }
    __syncthreads();  // barrier 2: h ready for next step
    xg = xg_next;
    g_cur = g_next;
  }

  // trailing decode for s = t1-1 (g_cur = gt[t1])
  if (tid < 64) {
    float v = p_lds[tid] + p_lds[tid + 64];
#pragma unroll
    for (int off = 32; off; off >>= 1) v += __shfl_down(v, off);
    if (tid == 0) {
      const float C = 1.f / (1.f + __expf(-(v + bd0)));
      nll0 -= g_cur * __logf(C + 1e-4f) +
              (1.f - g_cur) * __logf(1.f - C + 1e-4f);
    }
  }

  if (tid < 128) ws_h[(size_t)row * H_DIM + j] = h_lds[j];
  if (tid == 0)
    nll_part[row] = first ? nll0 : (nll_part[row] + nll0);
}

// ---------------------------------------------------------------------------
__global__ __launch_bounds__(512) void k_fin(const float* __restrict__ nll_part,
                                             float* __restrict__ out) {
  __shared__ float red[8];
  const int tid = threadIdx.x;
  float v = nll_part[tid];
#pragma unroll
  for (int off = 32; off; off >>= 1) v += __shfl_down(v, off);
  if ((tid & 63) == 0) red[tid >> 6] = v;
  __syncthreads();
  if (tid == 0) {
    float s = 0.f;
#pragma unroll
    for (int i = 0; i < 8; ++i) s += red[i];
    out[0] = s * (1.f / (512.f * 512.f));
  }
}

// ---------------------------------------------------------------------------
extern "C" void kernel_launch(void* const* d_in, const int* in_sizes, int n_in,
                              void* d_out, int out_size, void* d_ws,
                              size_t ws_size, hipStream_t stream) {
  const float* x    = (const float*)d_in[0];
  const float* gt   = (const float*)d_in[1];
  const float* Wih  = (const float*)d_in[2];
  const float* Whh  = (const float*)d_in[3];
  const float* bih  = (const float*)d_in[4];
  const float* bhh  = (const float*)d_in[5];
  const float* Wdec = (const float*)d_in[6];
  const float* bdec = (const float*)d_in[7];

  // ws layout: [0,2KB) nll_part[512]; [4KB,260KB) h state; then xp chunk
  float* nll_part = (float*)d_ws;
  float* ws_h = (float*)((char*)d_ws + 4096);
  const size_t xp_off = 4096 + (size_t)B_DIM * H_DIM * 4;  // 266240
  float* xp = (float*)((char*)d_ws + xp_off);

  const size_t chunk_bytes = (size_t)B_DIM * G_DIM * 4;  // per timestep
  size_t avail = ws_size > xp_off ? ws_size - xp_off : 0;
  int Tc = (int)(avail / chunk_bytes);
  if (Tc > 64) Tc = 64;        // keep xp chunk (<=48 MB) L3-resident
  if (Tc < 1) Tc = 1;

  for (int t0 = 0; t0 < STEPS; t0 += Tc) {
    int t1 = t0 + Tc;
    if (t1 > STEPS) t1 = STEPS;
    const int nt = t1 - t0;
    k_xproj<<<dim3(nt * 4, 6), dim3(256), 0, stream>>>(
        x + (size_t)t0 * B_DIM * I_DIM, Wih, bih, xp);
    k_rec<<<dim3(512), dim3(512), 0, stream>>>(
        xp, gt, Whh, bhh, Wdec, bdec, ws_h, nll_part, t0, t1, t0 == 0 ? 1 : 0);
  }
  k_fin<<<dim3(1), dim3(512), 0, stream>>>(nll_part, (float*)d_out);
}